// Round 1
// 1575.775 us; speedup vs baseline: 2.9565x; 2.9565x over previous
//
#include <hip/hip_runtime.h>
#include <cstddef>
#include <cstdint>

// Problem constants (Attention_layer_56590489092432)
#define B_   16
#define S_   512
#define D_   1024
#define H_   16
#define DH_  64
#define BS_  8192          // B_*S_
#define EPS_ 1e-5f

typedef __attribute__((ext_vector_type(8))) short bf16x8;   // 8 bf16 (4 VGPR)
typedef __attribute__((ext_vector_type(4))) short s16x4;
typedef __attribute__((ext_vector_type(4))) float f32x4;

// ---------------------------------------------------------------------------
// bf16 split helpers: v ~= hi + lo, both RNE bf16. hi*hi + hi*lo + lo*hi gives
// ~2^-17 relative error per product -> fp32-equivalent results.
// ---------------------------------------------------------------------------
__device__ __forceinline__ unsigned short f2bf(float f) {
    unsigned int u = __builtin_bit_cast(unsigned int, f);
    u = (u + 0x7FFFu + ((u >> 16) & 1u)) >> 16;
    return (unsigned short)u;
}
__device__ __forceinline__ float bf2f(unsigned short h) {
    unsigned int u = ((unsigned int)h) << 16;
    return __builtin_bit_cast(float, u);
}
__device__ __forceinline__ void splitbf(float v, short& hi, short& lo) {
    unsigned short h = f2bf(v);
    float r = v - bf2f(h);
    hi = (short)h;
    lo = (short)f2bf(r);
}

// async global->LDS, 16B per lane (dest must be wave-uniform base + lane*16)
__device__ __forceinline__ void gload16(const void* g, void* l) {
    __builtin_amdgcn_global_load_lds(
        (const __attribute__((address_space(1))) unsigned int*)g,
        (__attribute__((address_space(3))) unsigned int*)l, 16, 0, 0);
}

// ---------------------------------------------------------------------------
// Plane layout: 128x32 tiles of 4096 bf16, chunked as [frag16(8)][kc(4)][m16(16)][j(8)]
// -> global_load_lds copies a tile linearly; ds_read_b128 frag loads are
// perfectly linear per instruction (zero bank conflicts).
// offset within tile for (mloc,kloc):
//   (( (mloc>>4)*4 + (kloc>>3) )*16 + (mloc&15))*8 + (kloc&7)
// ---------------------------------------------------------------------------

// Core main loop: C(128x128) += A(128xK) * B(128xK)^T over nkt K-tiles of 32,
// split-bf16 (3 MFMAs per frag pair). 256 threads, 4 waves (2x2 of 64x64).
__device__ __forceinline__ void mainloop128(
    const short* __restrict__ Ah, const short* __restrict__ Al,
    const short* __restrict__ Bh, const short* __restrict__ Bl,
    int nkt, short* lds, f32x4 acc[4][4])
{
    const int t = threadIdx.x;
    const int wid = t >> 6, lane = t & 63;
    short* LAh = lds;
    short* LAl = lds + 4096;
    short* LBh = lds + 8192;
    short* LBl = lds + 12288;
    const int fa = (wid >> 1) * 4;
    const int fb = (wid & 1) * 4;
    for (int kt = 0; kt < nkt; ++kt) {
        const size_t go = (size_t)kt * 4096 + (size_t)t * 8;
        gload16(Ah + go,        LAh + t * 8);
        gload16(Ah + go + 2048, LAh + t * 8 + 2048);
        gload16(Al + go,        LAl + t * 8);
        gload16(Al + go + 2048, LAl + t * 8 + 2048);
        gload16(Bh + go,        LBh + t * 8);
        gload16(Bh + go + 2048, LBh + t * 8 + 2048);
        gload16(Bl + go,        LBl + t * 8);
        gload16(Bl + go + 2048, LBl + t * 8 + 2048);
        asm volatile("s_waitcnt vmcnt(0)" ::: "memory");
        __syncthreads();
        bf16x8 aH[4], aL[4];
        #pragma unroll
        for (int fm = 0; fm < 4; ++fm) {
            aH[fm] = *(const bf16x8*)(LAh + (fa + fm) * 512 + lane * 8);
            aL[fm] = *(const bf16x8*)(LAl + (fa + fm) * 512 + lane * 8);
        }
        #pragma unroll
        for (int fn = 0; fn < 4; ++fn) {
            bf16x8 bH = *(const bf16x8*)(LBh + (fb + fn) * 512 + lane * 8);
            bf16x8 bL = *(const bf16x8*)(LBl + (fb + fn) * 512 + lane * 8);
            #pragma unroll
            for (int fm = 0; fm < 4; ++fm) {
                acc[fm][fn] = __builtin_amdgcn_mfma_f32_16x16x32_bf16(aH[fm], bH, acc[fm][fn], 0, 0, 0);
                acc[fm][fn] = __builtin_amdgcn_mfma_f32_16x16x32_bf16(aH[fm], bL, acc[fm][fn], 0, 0, 0);
                acc[fm][fn] = __builtin_amdgcn_mfma_f32_16x16x32_bf16(aL[fm], bH, acc[fm][fn], 0, 0, 0);
            }
        }
        __syncthreads();
    }
}

// ---------------------------------------------------------------------------
// proj: [8192x1024] x [3072x1024]^T -> q/k/v, fused per-head LN (rows of 64),
// writes Q/K planes (per-z scores tiling) and V planes (row-major for vt).
// grid (64, 24)
// ---------------------------------------------------------------------------
__global__ __launch_bounds__(256, 3) void proj_kernel(
    const short* __restrict__ XPh, const short* __restrict__ XPl,
    const short* __restrict__ WTh, const short* __restrict__ WTl,
    const float* __restrict__ gq, const float* __restrict__ bq,
    const float* __restrict__ gk, const float* __restrict__ bk,
    const float* __restrict__ gv, const float* __restrict__ bv,
    short* __restrict__ QPh, short* __restrict__ QPl,
    short* __restrict__ KPh, short* __restrict__ KPl,
    short* __restrict__ VPh, short* __restrict__ VPl)
{
    __shared__ __align__(16) short lds[16384];
    const int mt = blockIdx.x, nt = blockIdx.y;
    f32x4 acc[4][4] = {};
    mainloop128(XPh + (size_t)mt * 131072, XPl + (size_t)mt * 131072,
                WTh + (size_t)nt * 131072, WTl + (size_t)nt * 131072,
                32, lds, acc);
    const int t = threadIdx.x, wid = t >> 6, lane = t & 63;
    const int g = lane >> 4, li = lane & 15;
    const int wm = (wid >> 1) * 64, wn = (wid & 1) * 64;
    const int n0 = nt * 128 + wn;            // 64-aligned -> one head per wave
    const int qkv = n0 >> 10;
    const int h = (n0 >> 6) & 15;
    const float* gam = qkv == 0 ? gq : (qkv == 1 ? gk : gv);
    const float* bet = qkv == 0 ? bq : (qkv == 1 ? bk : bv);
    float gm[4], bt[4];
    #pragma unroll
    for (int fn = 0; fn < 4; ++fn) { gm[fn] = gam[fn * 16 + li]; bt[fn] = bet[fn * 16 + li]; }
    #pragma unroll
    for (int fm = 0; fm < 4; ++fm) {
        #pragma unroll
        for (int r = 0; r < 4; ++r) {
            // per-row LN over the wave's 64 cols: row lives in lanes sharing g
            float s = acc[fm][0][r] + acc[fm][1][r] + acc[fm][2][r] + acc[fm][3][r];
            s += __shfl_xor(s, 1, 64); s += __shfl_xor(s, 2, 64);
            s += __shfl_xor(s, 4, 64); s += __shfl_xor(s, 8, 64);
            const float mean = s * (1.f / 64.f);
            float q = 0.f;
            #pragma unroll
            for (int fn = 0; fn < 4; ++fn) { const float d = acc[fm][fn][r] - mean; q += d * d; }
            q += __shfl_xor(q, 1, 64); q += __shfl_xor(q, 2, 64);
            q += __shfl_xor(q, 4, 64); q += __shfl_xor(q, 8, 64);
            const float rstd = rsqrtf(q * (1.f / 64.f) + EPS_);
            const int m = mt * 128 + wm + fm * 16 + g * 4 + r;
            const int b = m >> 9, srow = m & 511;
            const int z = b * 16 + h;
            #pragma unroll
            for (int fn = 0; fn < 4; ++fn) {
                const float val = (acc[fm][fn][r] - mean) * rstd * gm[fn] + bt[fn];
                short hi, lo; splitbf(val, hi, lo);
                const int e = fn * 16 + li;
                if (qkv == 2) {
                    const size_t o = (size_t)z * 32768 + (size_t)srow * 64 + e;
                    VPh[o] = hi; VPl[o] = lo;
                } else {
                    const size_t o = ((size_t)((z * 4 + (srow >> 7)) * 2 + (e >> 5))) * 4096
                                   + ((((srow >> 4) & 7) * 4 + ((e >> 3) & 3)) * 16 + (srow & 15)) * 8 + (e & 7);
                    if (qkv == 0) { QPh[o] = hi; QPl[o] = lo; }
                    else          { KPh[o] = hi; KPl[o] = lo; }
                }
            }
        }
    }
}

// ---------------------------------------------------------------------------
// mlp: C = relu(A*W + b). MODE 1: write bf16 planes (input of next mlp);
// MODE 2: write fp32. grid (64, 8)
// ---------------------------------------------------------------------------
template<int MODE>
__global__ __launch_bounds__(256, 3) void mlp_kernel(
    const short* __restrict__ Ah, const short* __restrict__ Al,
    const short* __restrict__ Bh, const short* __restrict__ Bl,
    const float* __restrict__ bias,
    short* __restrict__ OPh, short* __restrict__ OPl,
    float* __restrict__ OF)
{
    __shared__ __align__(16) short lds[16384];
    const int mt = blockIdx.x, nt = blockIdx.y;
    f32x4 acc[4][4] = {};
    mainloop128(Ah + (size_t)mt * 131072, Al + (size_t)mt * 131072,
                Bh + (size_t)nt * 131072, Bl + (size_t)nt * 131072, 32, lds, acc);
    const int t = threadIdx.x, wid = t >> 6, lane = t & 63;
    const int g = lane >> 4, li = lane & 15;
    const int wm = (wid >> 1) * 64, wn = (wid & 1) * 64;
    float bb[4];
    #pragma unroll
    for (int fn = 0; fn < 4; ++fn) bb[fn] = bias[nt * 128 + wn + fn * 16 + li];
    #pragma unroll
    for (int fm = 0; fm < 4; ++fm) {
        #pragma unroll
        for (int r = 0; r < 4; ++r) {
            const int m = mt * 128 + wm + fm * 16 + g * 4 + r;
            #pragma unroll
            for (int fn = 0; fn < 4; ++fn) {
                const int n = nt * 128 + wn + fn * 16 + li;
                float v = acc[fm][fn][r] + bb[fn];
                v = v > 0.f ? v : 0.f;
                if (MODE == 1) {
                    short hi, lo; splitbf(v, hi, lo);
                    const size_t o = ((size_t)mt * 32 + (n >> 5)) * 4096
                                   + ((((m >> 4) & 7) * 4 + ((n >> 3) & 3)) * 16 + (m & 15)) * 8 + (n & 7);
                    OPh[o] = hi; OPl[o] = lo;
                } else {
                    OF[(size_t)m * 1024 + n] = v;
                }
            }
        }
    }
}

// ---------------------------------------------------------------------------
// scores: per z, P = Qn*Kn^T * 0.125 -> maps[(h*B+b)][s][t]. grid (4,4,256)
// ---------------------------------------------------------------------------
__global__ __launch_bounds__(256, 3) void scores_kernel(
    const short* __restrict__ QPh, const short* __restrict__ QPl,
    const short* __restrict__ KPh, const short* __restrict__ KPl,
    float* __restrict__ mapsi)
{
    __shared__ __align__(16) short lds[16384];
    const int mt = blockIdx.x, nt = blockIdx.y, z = blockIdx.z;
    f32x4 acc[4][4] = {};
    const size_t ab = (size_t)(z * 4 + mt) * 8192;
    const size_t bb2 = (size_t)(z * 4 + nt) * 8192;
    mainloop128(QPh + ab, QPl + ab, KPh + bb2, KPl + bb2, 2, lds, acc);
    const int t = threadIdx.x, wid = t >> 6, lane = t & 63;
    const int g = lane >> 4, li = lane & 15;
    const int wm = (wid >> 1) * 64, wn = (wid & 1) * 64;
    const int zp = ((z & 15) << 4) | (z >> 4);     // h*B + b
    float* P = mapsi + (size_t)zp * (S_ * S_);
    #pragma unroll
    for (int fm = 0; fm < 4; ++fm) {
        #pragma unroll
        for (int r = 0; r < 4; ++r) {
            const int srow = mt * 128 + wm + fm * 16 + g * 4 + r;
            #pragma unroll
            for (int fn = 0; fn < 4; ++fn) {
                const int tc = nt * 128 + wn + fn * 16 + li;
                P[(size_t)srow * 512 + tc] = acc[fm][fn][r] * 0.125f;
            }
        }
    }
}

// ---------------------------------------------------------------------------
// o: per z, O = P * Vn (BM=128, BN=64, BK=32, K=512). A staged from maps fp32
// with in-register hi/lo conversion; B from transposed V planes via gload_lds.
// grid(1024) with XCD-colocating swizzle so all 4 m-blocks of a z share L2.
// ---------------------------------------------------------------------------
__global__ __launch_bounds__(256, 3) void o_kernel(
    const float* __restrict__ maps, const short* __restrict__ VTh,
    const short* __restrict__ VTl, float* __restrict__ O)
{
    __shared__ __align__(16) short lds[12288];
    const int bid = blockIdx.x;
    const int xcd = bid & 7, tt = bid >> 3;
    const int mt = tt & 3;
    const int z = (tt >> 2) * 8 + xcd;
    const int zp = ((z & 15) << 4) | (z >> 4);
    const float* P = maps + (size_t)zp * (S_ * S_);
    const short* Bh = VTh + (size_t)z * 32768;
    const short* Bl = VTl + (size_t)z * 32768;
    short* LAh = lds;
    short* LAl = lds + 4096;
    short* LBh = lds + 8192;
    short* LBl = lds + 10240;
    const int t = threadIdx.x, wid = t >> 6, lane = t & 63;
    const int fa = (wid >> 1) * 4, fb = (wid & 1) * 2;
    f32x4 acc[4][2] = {};
    for (int kt = 0; kt < 16; ++kt) {
        gload16(Bh + (size_t)kt * 2048 + t * 8, LBh + t * 8);
        gload16(Bl + (size_t)kt * 2048 + t * 8, LBl + t * 8);
        #pragma unroll
        for (int cc = 0; cc < 2; ++cc) {
            const int c = t + cc * 256;
            const int srow = mt * 128 + (c >> 6) * 16 + (c & 15);
            const int k0 = kt * 32 + ((c >> 4) & 3) * 8;
            const float* src = P + (size_t)srow * 512 + k0;
            const f32x4 v0 = *(const f32x4*)(src);
            const f32x4 v1 = *(const f32x4*)(src + 4);
            bf16x8 h8, l8;
            #pragma unroll
            for (int j = 0; j < 4; ++j) {
                short hi, lo;
                splitbf(v0[j], hi, lo); h8[j] = hi;     l8[j] = lo;
                splitbf(v1[j], hi, lo); h8[4 + j] = hi; l8[4 + j] = lo;
            }
            *(bf16x8*)(LAh + c * 8) = h8;
            *(bf16x8*)(LAl + c * 8) = l8;
        }
        asm volatile("s_waitcnt vmcnt(0)" ::: "memory");
        __syncthreads();
        bf16x8 aH[4], aL[4];
        #pragma unroll
        for (int fm = 0; fm < 4; ++fm) {
            aH[fm] = *(const bf16x8*)(LAh + (fa + fm) * 512 + lane * 8);
            aL[fm] = *(const bf16x8*)(LAl + (fa + fm) * 512 + lane * 8);
        }
        #pragma unroll
        for (int fn = 0; fn < 2; ++fn) {
            bf16x8 bH = *(const bf16x8*)(LBh + (fb + fn) * 512 + lane * 8);
            bf16x8 bL = *(const bf16x8*)(LBl + (fb + fn) * 512 + lane * 8);
            #pragma unroll
            for (int fm = 0; fm < 4; ++fm) {
                acc[fm][fn] = __builtin_amdgcn_mfma_f32_16x16x32_bf16(aH[fm], bH, acc[fm][fn], 0, 0, 0);
                acc[fm][fn] = __builtin_amdgcn_mfma_f32_16x16x32_bf16(aH[fm], bL, acc[fm][fn], 0, 0, 0);
                acc[fm][fn] = __builtin_amdgcn_mfma_f32_16x16x32_bf16(aL[fm], bH, acc[fm][fn], 0, 0, 0);
            }
        }
        __syncthreads();
    }
    const int b = z >> 4, h = z & 15;
    const int g = lane >> 4, li = lane & 15;
    #pragma unroll
    for (int fm = 0; fm < 4; ++fm) {
        #pragma unroll
        for (int r = 0; r < 4; ++r) {
            const int srow = mt * 128 + (wid >> 1) * 64 + fm * 16 + g * 4 + r;
            #pragma unroll
            for (int fn = 0; fn < 2; ++fn) {
                const int e = (wid & 1) * 32 + fn * 16 + li;
                O[((size_t)b * 512 + srow) * 1024 + h * 64 + e] = acc[fm][fn][r];
            }
        }
    }
}

// ---------------------------------------------------------------------------
// vt: transpose LN'd V planes [z][t][e] -> tiled [z][kt][fn][kc][n16][j]
// grid (256, 16)
// ---------------------------------------------------------------------------
__global__ __launch_bounds__(256) void vt_kernel(
    const short* __restrict__ VPh, const short* __restrict__ VPl,
    short* __restrict__ VTh, short* __restrict__ VTl)
{
    const int z = blockIdx.x, kt = blockIdx.y;
    __shared__ __align__(16) short Th[32][80];
    __shared__ __align__(16) short Tl[32][80];
    const int t = threadIdx.x;
    {
        const int row = t >> 3;
        const int e0 = (t & 7) * 8;
        const size_t src = (size_t)z * 32768 + (size_t)(kt * 32 + row) * 64 + e0;
        *(bf16x8*)&Th[row][e0] = *(const bf16x8*)(VPh + src);
        *(bf16x8*)&Tl[row][e0] = *(const bf16x8*)(VPl + src);
    }
    __syncthreads();
    {
        const int c = t;
        const int fn = c >> 6, kc = (c >> 4) & 3, n16 = c & 15;
        const int e = fn * 16 + n16;
        bf16x8 h8, l8;
        #pragma unroll
        for (int j = 0; j < 8; ++j) {
            h8[j] = Th[kc * 8 + j][e];
            l8[j] = Tl[kc * 8 + j][e];
        }
        const size_t o = ((size_t)z * 16 + kt) * 2048 + (size_t)c * 8;
        *(bf16x8*)(VTh + o) = h8;
        *(bf16x8*)(VTl + o) = l8;
    }
}

// ---------------------------------------------------------------------------
// ln over rows of 1024: out = LN(A+C)*g+b (fp32) + bf16 hi/lo planes (tiled).
// grid BS, block 256 (4 consecutive elements/thread).
// ---------------------------------------------------------------------------
__global__ __launch_bounds__(256) void ln_add_kernel(
    const float* __restrict__ A, const float* __restrict__ C,
    const float* __restrict__ g, const float* __restrict__ bb,
    float* __restrict__ out, short* __restrict__ Ph, short* __restrict__ Pl)
{
    const int m = blockIdx.x;
    const int t = threadIdx.x;
    const int wave = t >> 6, lane = t & 63;
    __shared__ float red1[4];
    __shared__ float red2[4];
    const int k0 = t * 4;
    const f32x4 va = *(const f32x4*)(A + (size_t)m * 1024 + k0);
    const f32x4 vc = *(const f32x4*)(C + (size_t)m * 1024 + k0);
    f32x4 v = va + vc;
    float s = v[0] + v[1] + v[2] + v[3];
    #pragma unroll
    for (int off = 32; off > 0; off >>= 1) s += __shfl_xor(s, off, 64);
    if (lane == 0) red1[wave] = s;
    __syncthreads();
    const float mean = (red1[0] + red1[1] + red1[2] + red1[3]) * (1.f / 1024.f);
    float q = 0.f;
    #pragma unroll
    for (int j = 0; j < 4; ++j) { const float d = v[j] - mean; q += d * d; }
    #pragma unroll
    for (int off = 32; off > 0; off >>= 1) q += __shfl_xor(q, off, 64);
    if (lane == 0) red2[wave] = q;
    __syncthreads();
    const float rstd = rsqrtf((red2[0] + red2[1] + red2[2] + red2[3]) * (1.f / 1024.f) + EPS_);
    const f32x4 gg = *(const f32x4*)(g + k0);
    const f32x4 bv = *(const f32x4*)(bb + k0);
    f32x4 o;
    s16x4 hi4, lo4;
    #pragma unroll
    for (int j = 0; j < 4; ++j) {
        o[j] = (v[j] - mean) * rstd * gg[j] + bv[j];
        short hi, lo; splitbf(o[j], hi, lo);
        hi4[j] = hi; lo4[j] = lo;
    }
    *(f32x4*)(out + (size_t)m * 1024 + k0) = o;
    const size_t po = ((size_t)(m >> 7) * 32 + (k0 >> 5)) * 4096
                    + ((((m >> 4) & 7) * 4 + ((k0 >> 3) & 3)) * 16 + (m & 15)) * 8 + (k0 & 7);
    *(s16x4*)(Ph + po) = hi4;
    *(s16x4*)(Pl + po) = lo4;
}

// block-0 input -> planes (no LN). grid BS.
__global__ __launch_bounds__(256) void cvt_kernel(
    const float* __restrict__ X, short* __restrict__ Ph, short* __restrict__ Pl)
{
    const int m = blockIdx.x;
    const int t = threadIdx.x;
    const int k0 = t * 4;
    const f32x4 v = *(const f32x4*)(X + (size_t)m * 1024 + k0);
    s16x4 hi4, lo4;
    #pragma unroll
    for (int j = 0; j < 4; ++j) { short hi, lo; splitbf(v[j], hi, lo); hi4[j] = hi; lo4[j] = lo; }
    const size_t po = ((size_t)(m >> 7) * 32 + (k0 >> 5)) * 4096
                    + ((((m >> 4) & 7) * 4 + ((k0 >> 3) & 3)) * 16 + (m & 15)) * 8 + (k0 & 7);
    *(s16x4*)(Ph + po) = hi4;
    *(s16x4*)(Pl + po) = lo4;
}

// Wq/Wk/Wv (H,D,dh) -> transposed tiled planes [n=qkv*1024+h*64+e][k=d]. grid (24,32)
__global__ __launch_bounds__(256) void prep_wqkv_kernel(
    const float* __restrict__ Wq, const float* __restrict__ Wk,
    const float* __restrict__ Wv, short* __restrict__ WTh, short* __restrict__ WTl)
{
    const int nt = blockIdx.x;    // 0..23
    const int kt = blockIdx.y;    // 0..31
    const int qkv = nt >> 3;
    const float* W = qkv == 0 ? Wq : (qkv == 1 ? Wk : Wv);
    const int t = threadIdx.x;
    short* oh = WTh + ((size_t)nt * 32 + kt) * 4096;
    short* ol = WTl + ((size_t)nt * 32 + kt) * 4096;
    #pragma unroll
    for (int cc = 0; cc < 2; ++cc) {
        const int c = t + cc * 256;
        const int nloc = (c >> 6) * 16 + (c & 15);
        const int nq = (nt & 7) * 128 + nloc;
        const int h = nq >> 6, e = nq & 63;
        const int d0 = kt * 32 + ((c >> 4) & 3) * 8;
        bf16x8 h8, l8;
        #pragma unroll
        for (int j = 0; j < 8; ++j) {
            const float v = W[((size_t)h * 1024 + d0 + j) * 64 + e];
            short hi, lo; splitbf(v, hi, lo);
            h8[j] = hi; l8[j] = lo;
        }
        *(bf16x8*)(oh + c * 8) = h8;
        *(bf16x8*)(ol + c * 8) = l8;
    }
}

// mW (L,D,D) -> transposed tiled planes per layer. grid (8,32,2)
__global__ __launch_bounds__(256) void prep_mw_kernel(
    const float* __restrict__ Wm, short* __restrict__ Mh, short* __restrict__ Ml)
{
    const int nt = blockIdx.x;   // 0..7
    const int kt = blockIdx.y;   // 0..31
    const int l  = blockIdx.z;   // 0..1
    const float* W = Wm + (size_t)l * 1048576;
    short* oh = Mh + (size_t)l * 1048576 + ((size_t)nt * 32 + kt) * 4096;
    short* ol = Ml + (size_t)l * 1048576 + ((size_t)nt * 32 + kt) * 4096;
    const int t = threadIdx.x;
    #pragma unroll
    for (int cc = 0; cc < 2; ++cc) {
        const int c = t + cc * 256;
        const int n = nt * 128 + (c >> 6) * 16 + (c & 15);
        const int k0 = kt * 32 + ((c >> 4) & 3) * 8;
        bf16x8 h8, l8;
        #pragma unroll
        for (int j = 0; j < 8; ++j) {
            const float v = W[(size_t)(k0 + j) * 1024 + n];
            short hi, lo; splitbf(v, hi, lo);
            h8[j] = hi; l8[j] = lo;
        }
        *(bf16x8*)(oh + c * 8) = h8;
        *(bf16x8*)(ol + c * 8) = l8;
    }
}

// ---------------------------------------------------------------------------
extern "C" void kernel_launch(void* const* d_in, const int* in_sizes, int n_in,
                              void* d_out, int out_size, void* d_ws, size_t ws_size,
                              hipStream_t stream)
{
    const float* inputs = (const float*)d_in[0];
    const float* Wq  = (const float*)d_in[1];
    const float* Wk  = (const float*)d_in[2];
    const float* Wv  = (const float*)d_in[3];
    const float* qg  = (const float*)d_in[4];
    const float* qb  = (const float*)d_in[5];
    const float* kg  = (const float*)d_in[6];
    const float* kb  = (const float*)d_in[7];
    const float* vg  = (const float*)d_in[8];
    const float* vb  = (const float*)d_in[9];
    const float* l0g = (const float*)d_in[10];
    const float* l0b = (const float*)d_in[11];
    const float* l1g = (const float*)d_in[12];
    const float* l1b = (const float*)d_in[13];
    const float* mW  = (const float*)d_in[14];
    const float* mB  = (const float*)d_in[15];

    float* xout = (float*)d_out;                       // (B,S,D)
    float* maps = xout + (size_t)BS_ * D_;             // (NB, H*B, S, S)

    // workspace layout (bytes), total 188,743,680 (< 201MB used previously)
    char* ws = (char*)d_ws;
    short* XPh = (short*)(ws);                         // x planes / VT planes
    short* XPl = (short*)(ws + 16777216);
    short* QPh = (short*)(ws + 33554432);              // Qn planes / HT planes
    short* QPl = (short*)(ws + 50331648);
    short* KPh = (short*)(ws + 67108864);              // Kn planes / NEW planes
    short* KPl = (short*)(ws + 83886080);
    float* NEW = (float*)(ws + 100663296);             // NEW fp32 (aliases VP)
    short* VPh = (short*)(ws + 100663296);             // Vn planes (dead before NEW)
    short* VPl = (short*)(ws + 117440512);
    float* OF  = (float*)(ws + 134217728);             // attn out / mlp2 out fp32
    short* WTh = (short*)(ws + 167772160);             // qkv weight planes
    short* WTl = (short*)(ws + 174063616);
    short* MWh = (short*)(ws + 180355072);             // mlp weight planes (2 layers)
    short* MWl = (short*)(ws + 184549376);
    short* VTh = XPh;                                  // V^T planes alias x planes
    short* VTl = XPl;

    const dim3 blk(256);
    for (int i = 0; i < 2; ++i) {
        const float* xin = (i == 0) ? inputs : xout;
        float* mapsi = maps + (size_t)i * H_ * B_ * S_ * S_;

        if (i == 0)
            cvt_kernel<<<dim3(BS_), blk, 0, stream>>>(inputs, XPh, XPl);

        prep_wqkv_kernel<<<dim3(24, 32), blk, 0, stream>>>(
            Wq + (size_t)i * H_ * D_ * DH_, Wk + (size_t)i * H_ * D_ * DH_,
            Wv + (size_t)i * H_ * D_ * DH_, WTh, WTl);
        prep_mw_kernel<<<dim3(8, 32, 2), blk, 0, stream>>>(
            mW + (size_t)i * 2 * D_ * D_, MWh, MWl);

        proj_kernel<<<dim3(64, 24), blk, 0, stream>>>(
            XPh, XPl, WTh, WTl,
            qg + i * DH_, qb + i * DH_, kg + i * DH_, kb + i * DH_,
            vg + i * DH_, vb + i * DH_,
            QPh, QPl, KPh, KPl, VPh, VPl);

        vt_kernel<<<dim3(256, 16), blk, 0, stream>>>(VPh, VPl, VTh, VTl);

        scores_kernel<<<dim3(4, 4, 256), blk, 0, stream>>>(QPh, QPl, KPh, KPl, mapsi);

        o_kernel<<<dim3(1024), blk, 0, stream>>>(mapsi, VTh, VTl, OF);

        ln_add_kernel<<<dim3(BS_), blk, 0, stream>>>(
            xin, OF, l0g + i * D_, l0b + i * D_, NEW, KPh, KPl);

        mlp_kernel<1><<<dim3(64, 8), blk, 0, stream>>>(
            KPh, KPl, MWh, MWl, mB + (size_t)(i * 2 + 0) * D_, QPh, QPl, (float*)nullptr);
        mlp_kernel<2><<<dim3(64, 8), blk, 0, stream>>>(
            QPh, QPl, MWh + 1048576, MWl + 1048576, mB + (size_t)(i * 2 + 1) * D_,
            (short*)nullptr, (short*)nullptr, OF);

        ln_add_kernel<<<dim3(BS_), blk, 0, stream>>>(
            NEW, OF, l1g + i * D_, l1b + i * D_, xout, XPh, XPl);
    }
}